// Round 2
// baseline (416.723 us; speedup 1.0000x reference)
//
#include <hip/hip_runtime.h>
#include <stdint.h>

// out[(b,m),n] = (sum_k x_q[(b,m),k] * w[n,k]) * sx[(b,m)] * ws[n] + bias[n]
// HARNESS NOTE: integer inputs arrive as int32 buffers (one value per 4 bytes).
// Pass 1 packs them to int8 in d_ws; pass 2 is the i8 MFMA GEMM.
#define MROWS 8192
#define K_DIM 4096
#define N_DIM 4096
#define BM 128
#define BN 128
#define BK 64   // bytes of K per stage (int8)

#define X_ELEMS (MROWS * K_DIM)          // 33,554,432
#define W_ELEMS (N_DIM * K_DIM)          // 16,777,216

typedef __attribute__((ext_vector_type(4))) int int4v;

#define GLOAD_LDS16(gptr, lptr)                                                   \
    __builtin_amdgcn_global_load_lds((const __attribute__((address_space(1))) void*)(gptr), \
                                     (__attribute__((address_space(3))) void*)(lptr), 16, 0, 0)

// ---- pass 1: int32 -> packed int8 ------------------------------------------
// one lane: 16 B load (4 int32) -> 4 B store. Fully coalesced both sides.
__global__ __launch_bounds__(256) void pack_i32_to_i8(
    const int4v* __restrict__ src, int* __restrict__ dst, int n4)
{
    int i = blockIdx.x * blockDim.x + threadIdx.x;
    if (i >= n4) return;
    int4v v = src[i];
    unsigned p = (unsigned)(v[0] & 0xFF)
               | ((unsigned)(v[1] & 0xFF) << 8)
               | ((unsigned)(v[2] & 0xFF) << 16)
               | ((unsigned)(v[3] & 0xFF) << 24);
    dst[i] = (int)p;
}

// ---- pass 2: i8 GEMM + dequant epilogue ------------------------------------
__global__ __launch_bounds__(256) void i8gemm_dq_kernel(
    const int8_t* __restrict__ xq,   // (8192, 4096) packed i8
    const float*  __restrict__ sx,   // (8192,)
    const int8_t* __restrict__ wt,   // (4096, 4096) packed i8 (row = n)
    const float*  __restrict__ ws,   // (4096,)
    const float*  __restrict__ bias, // (4096,)
    float*        __restrict__ out)  // (8192, 4096) f32
{
    __shared__ __align__(16) int8_t lsA[BM * BK];  // 8 KB
    __shared__ __align__(16) int8_t lsB[BN * BK];  // 8 KB

    const int tid  = threadIdx.x;
    const int wave = tid >> 6;
    const int lane = tid & 63;

    // 32 col-tiles (N/128), 64 row-tiles (8192/128); consecutive blocks share a
    // row tile so the x-tile stays hot in L2 across the 32-block group.
    const int ct = blockIdx.x & 31;
    const int rt = blockIdx.x >> 5;

    const int wr = wave >> 1;   // which 64-row half of the 128-tile
    const int wc = wave & 1;    // which 64-col half

    // staging: per GLOAD_LDS16, 64 lanes x 16 B = 16 tile rows (4 lanes/row).
    // LDS dest is wave-uniform base + lane*16 -> row-major (stride BK) layout.
    const int srow = wave * 16 + (lane >> 2);
    const int scol = (lane & 3) * 16;
    const int8_t* gA = xq + (size_t)(rt * BM + srow) * K_DIM + scol;
    const int8_t* gB = wt + (size_t)(ct * BN + srow) * K_DIM + scol;
    int8_t* lA = lsA + wave * 1024;
    int8_t* lB = lsB + wave * 1024;

    // A/B frag for 16x16x64 i8 (assumed contiguous-16, mirrors verified bf16
    // 16x16x32 contiguous-8): lane holds 16 consecutive K-bytes of row
    // (lane&15), chunk (lane>>4)*16.
    const int mrow = lane & 15;
    const int kch  = (lane >> 4) * 16;

    int4v acc[4][4] = {};   // 4x4 of 16x16 int32 accumulators per wave

    const int kIters = K_DIM / BK;  // 64
    for (int kt = 0; kt < kIters; ++kt) {
        GLOAD_LDS16(gA,              lA);
        GLOAD_LDS16(gA + 64 * K_DIM, lA + 4096);
        GLOAD_LDS16(gB,              lB);
        GLOAD_LDS16(gB + 64 * K_DIM, lB + 4096);
        gA += BK;
        gB += BK;
        __syncthreads();   // drains vmcnt -> LDS tiles valid

        int4v afrag[4], bfrag[4];
        #pragma unroll
        for (int i = 0; i < 4; ++i)
            afrag[i] = *(const int4v*)(lsA + (wr * 64 + i * 16 + mrow) * BK + kch);
        #pragma unroll
        for (int j = 0; j < 4; ++j)
            bfrag[j] = *(const int4v*)(lsB + (wc * 64 + j * 16 + mrow) * BK + kch);

        #pragma unroll
        for (int i = 0; i < 4; ++i)
            #pragma unroll
            for (int j = 0; j < 4; ++j)
                acc[i][j] = __builtin_amdgcn_mfma_i32_16x16x64_i8(
                                afrag[i], bfrag[j], acc[i][j], 0, 0, 0);

        __syncthreads();   // before next stage overwrites LDS
    }

    // epilogue: C/D layout col=lane&15, row=(lane>>4)*4+reg (HW-verified,
    // dtype-independent).
    const int row_base = rt * BM + wr * 64;
    const int col_base = ct * BN + wc * 64;
    const int crow = (lane >> 4) * 4;
    const int ccol = lane & 15;

    float wsc[4], bsc[4];
    #pragma unroll
    for (int j = 0; j < 4; ++j) {
        const int c = col_base + j * 16 + ccol;
        wsc[j] = ws[c];
        bsc[j] = bias[c];
    }

    #pragma unroll
    for (int i = 0; i < 4; ++i) {
        const int r0 = row_base + i * 16 + crow;
        float sx4[4];
        #pragma unroll
        for (int r = 0; r < 4; ++r) sx4[r] = sx[r0 + r];
        #pragma unroll
        for (int j = 0; j < 4; ++j) {
            const int c = col_base + j * 16 + ccol;
            float* o = out + (size_t)r0 * N_DIM + c;
            #pragma unroll
            for (int r = 0; r < 4; ++r)
                o[(size_t)r * N_DIM] = (float)acc[i][j][r] * sx4[r] * wsc[j] + bsc[j];
        }
    }
}

extern "C" void kernel_launch(void* const* d_in, const int* in_sizes, int n_in,
                              void* d_out, int out_size, void* d_ws, size_t ws_size,
                              hipStream_t stream) {
    const int*   xq32 = (const int*)d_in[0];    // int inputs arrive as int32
    const float* sx   = (const float*)d_in[1];
    const int*   wt32 = (const int*)d_in[2];
    const float* ws   = (const float*)d_in[3];
    const float* bias = (const float*)d_in[4];
    float* out = (float*)d_out;

    int8_t* xq8 = (int8_t*)d_ws;                 // 33.5 MB
    int8_t* wt8 = xq8 + (size_t)X_ELEMS;         // 16.8 MB  (total 50.3 MB of ws)

    // pass 1: pack
    {
        int n4x = X_ELEMS / 4;   // 8,388,608
        int n4w = W_ELEMS / 4;   // 4,194,304
        pack_i32_to_i8<<<n4x / 256, 256, 0, stream>>>((const int4v*)xq32, (int*)xq8, n4x);
        pack_i32_to_i8<<<n4w / 256, 256, 0, stream>>>((const int4v*)wt32, (int*)wt8, n4w);
    }

    // pass 2: GEMM
    dim3 grid((MROWS / BM) * (N_DIM / BN));  // 64 * 32 = 2048 blocks
    i8gemm_dq_kernel<<<grid, 256, 0, stream>>>(xq8, sx, wt8, ws, bias, out);
}